// Round 4
// baseline (127.609 us; speedup 1.0000x reference)
//
#include <hip/hip_runtime.h>

typedef unsigned short u16;
typedef unsigned int u32;
typedef float f32x4 __attribute__((ext_vector_type(4)));
typedef short s16x8 __attribute__((ext_vector_type(8)));

#define LSEQ 2048
#define QIN 512
#define VIN 1024
#define KCAT 704
#define KEFF 2560
#define NORMS 0.10206207261596575f  // 1/sqrt(96)

__device__ __forceinline__ u16 f2bf(float f) {
  u32 u = __float_as_uint(f);
  u = (u + 0x7fffu + ((u >> 16) & 1u)) >> 16;  // RNE
  return (u16)u;
}
__device__ __forceinline__ float bf2f(u16 v) {
  return __uint_as_float(((u32)v) << 16);
}

__device__ __forceinline__ s16x8 load8cvt(const float* __restrict__ p) {
  float4 a = *(const float4*)p;
  float4 b = *(const float4*)(p + 4);
  s16x8 r;
  r[0] = (short)f2bf(a.x); r[1] = (short)f2bf(a.y);
  r[2] = (short)f2bf(a.z); r[3] = (short)f2bf(a.w);
  r[4] = (short)f2bf(b.x); r[5] = (short)f2bf(b.y);
  r[6] = (short)f2bf(b.z); r[7] = (short)f2bf(b.w);
  return r;
}

// Fragment-linear index for a weight matrix W[N=96][K]:
// element W[o][k] -> ((kc*6 + nt)*64 + kg*16 + ln)*8 + j
__device__ __forceinline__ size_t wfrag_idx(int o, int k) {
  int kc = k >> 5, kg = (k >> 3) & 3, j = k & 7;
  int nt = o >> 4, ln = o & 15;
  return ((size_t)(kc * 6 + nt) * 64 + kg * 16 + ln) * 8 + j;
}

// ---------------------------------------------------------------------------
// Kernel 1: prep (weights only).  Folds conv3/conv5+k_w into W_eff (frag
// layout) + b_eff; converts q_w/v_w to frag-bf16.
// blocks: [0,960) W_eff, 960 b_eff, [961,1153) q_w, [1153,1537) v_w.
// ---------------------------------------------------------------------------
__global__ __launch_bounds__(256) void prep_kernel(
    const float* __restrict__ q_w, const float* __restrict__ k_w,
    const float* __restrict__ k_b, const float* __restrict__ v_w,
    const float* __restrict__ cn3_w, const float* __restrict__ cn3_b,
    const float* __restrict__ cn5_w, const float* __restrict__ cn5_b,
    u16* __restrict__ wefff, float* __restrict__ beff,
    u16* __restrict__ qwf, u16* __restrict__ vwf) {
  int blk = blockIdx.x, tid = threadIdx.x;
  if (blk < 960) {                      // W_eff: 96*2560 elems
    int e = blk * 256 + tid;
    int o = e / KEFF;
    int k = e % KEFF;
    int t = k >> 9;
    int c = k & 511;
    const float* kwo = k_w + o * KCAT;
    float acc = (t == 2) ? kwo[c] : 0.f;
    if (t >= 1 && t <= 3) {
      const float* c3 = cn3_w + c * 3 + (t - 1);   // cn3_w[j][c][t-1]
      #pragma unroll 8
      for (int j = 0; j < 96; ++j) acc += kwo[512 + j] * c3[j * 1536];
    }
    const float* c5 = cn5_w + c * 5 + t;           // cn5_w[j][c][t]
    #pragma unroll 8
    for (int j = 0; j < 96; ++j) acc += kwo[608 + j] * c5[j * 2560];
    wefff[wfrag_idx(o, k)] = f2bf(acc);
  } else if (blk == 960) {              // b_eff
    if (tid < 96) {
      const float* kwo = k_w + tid * KCAT;
      float b = k_b[tid];
      for (int j = 0; j < 96; ++j)
        b += kwo[512 + j] * cn3_b[j] + kwo[608 + j] * cn5_b[j];
      beff[tid] = b;
    }
  } else if (blk < 1153) {              // q_w -> frag bf16 (96*512)
    int e = (blk - 961) * 256 + tid;
    int o = e >> 9, k = e & 511;
    qwf[wfrag_idx(o, k)] = f2bf(q_w[e]);
  } else {                              // v_w -> frag bf16 (96*1024)
    int e = (blk - 1153) * 256 + tid;
    int o = e >> 10, k = e & 1023;
    vwf[wfrag_idx(o, k)] = f2bf(v_w[e]);
  }
}

// ---------------------------------------------------------------------------
// Kernel 2: K-split projection GEMM, frag-layout weights & outputs, f32 A
// converted inline.  Block = 16 output rows; NW waves each own a K-slice
// (MODE 1: one conv tap, A rows shifted by wid-2).
// MODE 0: Q (A=evo);  MODE 1: K-conv (A=evo shifted);  MODE 2: V (A=plm,
// writes Vfrag + Vb row-major bf16).
// ---------------------------------------------------------------------------
template <int NW, int KPW, int AKD, int MODE, int UNR>
__global__ __launch_bounds__(NW * 64, 2) void proj_split(
    const float* __restrict__ Xf, const u16* __restrict__ Wf,
    const float* __restrict__ bias, u16* __restrict__ OutFrag,
    u16* __restrict__ Vb) {
  __shared__ float Ls[NW][16][100];
  int bx = blockIdx.x, bb = blockIdx.y;
  int tid = threadIdx.x;
  int wid = tid >> 6, lane = tid & 63, ln = lane & 15, kg = lane >> 4;
  int srow = bx * 16 + ln + (MODE == 1 ? wid - 2 : 0);
  bool rowok = (srow >= 0) && (srow < LSEQ);
  const float* xf = Xf + ((size_t)bb * LSEQ + (rowok ? srow : 0)) * AKD +
                    (MODE == 1 ? 0 : wid * KPW);
  f32x4 acc[6];
  #pragma unroll
  for (int nt = 0; nt < 6; ++nt) acc[nt] = (f32x4){0.f, 0.f, 0.f, 0.f};

  #pragma unroll UNR
  for (int kc = 0; kc < KPW / 32; ++kc) {
    s16x8 a = (s16x8){0, 0, 0, 0, 0, 0, 0, 0};
    if (MODE != 1 || rowok) a = load8cvt(xf + kc * 32 + kg * 8);
    const u16* wp = Wf + (size_t)(wid * (KPW / 32) + kc) * 3072 + lane * 8;
    #pragma unroll
    for (int nt = 0; nt < 6; ++nt) {
      s16x8 bf = *(const s16x8*)&wp[(size_t)nt * 512];
      acc[nt] = __builtin_amdgcn_mfma_f32_16x16x32_bf16(a, bf, acc[nt], 0, 0, 0);
    }
  }
  #pragma unroll
  for (int nt = 0; nt < 6; ++nt)
    #pragma unroll
    for (int r = 0; r < 4; ++r)
      Ls[wid][kg * 4 + r][nt * 16 + ln] = acc[nt][r];
  __syncthreads();

  if (tid < 192) {
    if constexpr (MODE == 0 || MODE == 1) {
      int r = tid / 12, cg = tid % 12;
      s16x8 ov;
      #pragma unroll
      for (int e = 0; e < 8; ++e) {
        int c = cg * 8 + e;
        float s = bias[c];
        #pragma unroll
        for (int w = 0; w < NW; ++w) s += Ls[w][r][c];
        ov[e] = (short)f2bf(s);
      }
      size_t qt = (size_t)bb * 128 + bx;
      *(s16x8*)&OutFrag[((qt * 3 + (cg >> 2)) * 64 + (cg & 3) * 16 + r) * 8] = ov;
    } else {
      int r = tid / 12, cg = tid % 12;
      s16x8 ov;
      #pragma unroll
      for (int e = 0; e < 8; ++e) {
        int c = cg * 8 + e;
        float s = bias[c];
        #pragma unroll
        for (int w = 0; w < NW; ++w) s += Ls[w][r][c];
        ov[e] = (short)f2bf(s);
      }
      *(s16x8*)&Vb[((size_t)bb * LSEQ + bx * 16 + r) * 96 + cg * 8] = ov;
      // Vfrag: thread owns feature c, 8 consecutive keys
      int c = tid >> 1, kb = tid & 1;
      s16x8 fv;
      #pragma unroll
      for (int e = 0; e < 8; ++e) {
        int row = kb * 8 + e;
        float s = bias[c];
        #pragma unroll
        for (int w = 0; w < NW; ++w) s += Ls[w][row][c];
        fv[e] = (short)f2bf(s);
      }
      int keyg = bx * 16 + kb * 8;
      int ktv = keyg >> 5, kgv = (keyg >> 3) & 3;
      *(s16x8*)&OutFrag[((((size_t)bb * 64 + ktv) * 6 + (c >> 4)) * 64 +
                         kgv * 16 + (c & 15)) * 8] = fv;
    }
  }
}

// ---------------------------------------------------------------------------
// Kernel 3: flash attention + "+V", key-split across 4 waves, all operands in
// fragment layout -> every global load is a coalesced 1KB wave load.
// 1D grid 1024, XCD-swizzled so each batch lives on one XCD's L2.
// ---------------------------------------------------------------------------
__global__ __launch_bounds__(256) void attn_kernel(
    const u16* __restrict__ Qf, const u16* __restrict__ Kf,
    const u16* __restrict__ Vfr, const u16* __restrict__ Vb,
    const int* __restrict__ seqlen, float* __restrict__ out) {
  __shared__ u16 Ps[4][16][40];       // per-wave P scratch
  __shared__ float Cacc[4][16][97];   // partial O
  __shared__ float Cml[4][16][2];     // partial m, l

  int bid = blockIdx.x;
  int swz = (bid & 7) * 128 + (bid >> 3);   // XCD x -> batch x
  int bb = swz >> 7, bx = swz & 127;
  int tid = threadIdx.x;
  int wid = tid >> 6, lane = tid & 63, ln = lane & 15, kg = lane >> 4;
  int n = seqlen[bb];
  int nkc = (n + 31) >> 5;

  size_t qt = (size_t)bb * 128 + bx;
  s16x8 aQ[3];
  #pragma unroll
  for (int kk = 0; kk < 3; ++kk)
    aQ[kk] = *(const s16x8*)&Qf[((qt * 3 + kk) * 64 + lane) * 8];

  float m[4], lsum[4];
  f32x4 acc[6];
  #pragma unroll
  for (int r = 0; r < 4; ++r) { m[r] = -1e30f; lsum[r] = 0.f; }
  #pragma unroll
  for (int nt = 0; nt < 6; ++nt) acc[nt] = (f32x4){0.f, 0.f, 0.f, 0.f};

  for (int kc = wid; kc < nkc; kc += 4) {
    int key0 = kc * 32;
    // ---- S = Q K^T; K-frags: two 16-key tiles, 3KB contiguous each ----
    const u16* kf0 = Kf + (((size_t)bb * 128 + kc * 2) * 3 * 64) * 8 + lane * 8;
    f32x4 s0 = (f32x4){0.f, 0.f, 0.f, 0.f};
    f32x4 s1 = (f32x4){0.f, 0.f, 0.f, 0.f};
    #pragma unroll
    for (int kk = 0; kk < 3; ++kk) {
      s16x8 b0 = *(const s16x8*)&kf0[(size_t)kk * 512];
      s0 = __builtin_amdgcn_mfma_f32_16x16x32_bf16(aQ[kk], b0, s0, 0, 0, 0);
      s16x8 b1 = *(const s16x8*)&kf0[(size_t)(3 + kk) * 512];
      s1 = __builtin_amdgcn_mfma_f32_16x16x32_bf16(aQ[kk], b1, s1, 0, 0, 0);
    }

    // ---- mask + scale, online softmax ----
    bool v0 = (key0 + ln) < n;
    bool v1 = (key0 + 16 + ln) < n;
    float sv0[4], sv1[4], mx[4];
    #pragma unroll
    for (int r = 0; r < 4; ++r) {
      sv0[r] = v0 ? s0[r] * NORMS : -1e30f;
      sv1[r] = v1 ? s1[r] * NORMS : -1e30f;
      mx[r] = fmaxf(sv0[r], sv1[r]);
    }
    #pragma unroll
    for (int r = 0; r < 4; ++r) {
      mx[r] = fmaxf(mx[r], __shfl_xor(mx[r], 1, 16));
      mx[r] = fmaxf(mx[r], __shfl_xor(mx[r], 2, 16));
      mx[r] = fmaxf(mx[r], __shfl_xor(mx[r], 4, 16));
      mx[r] = fmaxf(mx[r], __shfl_xor(mx[r], 8, 16));
    }
    float fac[4], p0[4], p1[4], rs[4];
    #pragma unroll
    for (int r = 0; r < 4; ++r) {
      float mn = fmaxf(m[r], mx[r]);
      fac[r] = __expf(m[r] - mn);
      p0[r] = __expf(sv0[r] - mn);
      p1[r] = __expf(sv1[r] - mn);
      rs[r] = p0[r] + p1[r];
      m[r] = mn;
    }
    #pragma unroll
    for (int r = 0; r < 4; ++r) {
      rs[r] += __shfl_xor(rs[r], 1, 16);
      rs[r] += __shfl_xor(rs[r], 2, 16);
      rs[r] += __shfl_xor(rs[r], 4, 16);
      rs[r] += __shfl_xor(rs[r], 8, 16);
      lsum[r] = lsum[r] * fac[r] + rs[r];
    }
    #pragma unroll
    for (int nt = 0; nt < 6; ++nt)
      #pragma unroll
      for (int r = 0; r < 4; ++r) acc[nt][r] *= fac[r];

    // ---- P (D-layout) -> per-wave LDS -> A-frag (bf16) ----
    u16* Pw = &Ps[wid][0][0];
    #pragma unroll
    for (int r = 0; r < 4; ++r) {
      Pw[(kg * 4 + r) * 40 + ln] = f2bf(p0[r]);
      Pw[(kg * 4 + r) * 40 + 16 + ln] = f2bf(p1[r]);
    }
    s16x8 pa = *(const s16x8*)&Pw[ln * 40 + kg * 8];

    // ---- acc += P @ V; V-frags 6KB contiguous ----
    const u16* vf = Vfr + (((size_t)bb * 64 + kc) * 6 * 64) * 8 + lane * 8;
    #pragma unroll
    for (int nt = 0; nt < 6; ++nt) {
      s16x8 bv = *(const s16x8*)&vf[(size_t)nt * 512];
      acc[nt] = __builtin_amdgcn_mfma_f32_16x16x32_bf16(pa, bv, acc[nt], 0, 0, 0);
    }
  }

  // ---- write partials ----
  #pragma unroll
  for (int nt = 0; nt < 6; ++nt)
    #pragma unroll
    for (int r = 0; r < 4; ++r)
      Cacc[wid][kg * 4 + r][nt * 16 + ln] = acc[nt][r];
  if (ln == 0) {
    #pragma unroll
    for (int r = 0; r < 4; ++r) {
      Cml[wid][kg * 4 + r][0] = m[r];
      Cml[wid][kg * 4 + r][1] = lsum[r];
    }
  }
  __syncthreads();

  // ---- combine 4 key-split partials + "+V" ----
  size_t obase = ((size_t)bb * LSEQ + bx * 16) * 96;
  for (int i = tid; i < 1536; i += 256) {
    int row = i / 96;
    float mg = -1e30f;
    #pragma unroll
    for (int w = 0; w < 4; ++w) mg = fmaxf(mg, Cml[w][row][0]);
    float lg = 0.f, av = 0.f;
    #pragma unroll
    for (int w = 0; w < 4; ++w) {
      float e = __expf(Cml[w][row][0] - mg);
      lg += Cml[w][row][1] * e;
      av += Cacc[w][row][i - row * 96] * e;
    }
    out[obase + i] = av / lg + bf2f(Vb[obase + i]);
  }
}

// ---------------------------------------------------------------------------
extern "C" void kernel_launch(void* const* d_in, const int* in_sizes, int n_in,
                              void* d_out, int out_size, void* d_ws,
                              size_t ws_size, hipStream_t stream) {
  const float* plm   = (const float*)d_in[0];
  const float* evo   = (const float*)d_in[1];
  const int* seqlen  = (const int*)d_in[2];
  const float* q_w   = (const float*)d_in[3];
  const float* q_b   = (const float*)d_in[4];
  const float* k_w   = (const float*)d_in[5];
  const float* k_b   = (const float*)d_in[6];
  const float* v_w   = (const float*)d_in[7];
  const float* v_b   = (const float*)d_in[8];
  const float* cn3_w = (const float*)d_in[9];
  const float* cn3_b = (const float*)d_in[10];
  const float* cn5_w = (const float*)d_in[11];
  const float* cn5_b = (const float*)d_in[12];

  char* ws = (char*)d_ws;
  u16* wefff  = (u16*)(ws + 0);          // 491520
  float* beff = (float*)(ws + 491520);   // 512
  u16* qwf    = (u16*)(ws + 492032);     // 98304
  u16* vwf    = (u16*)(ws + 590336);     // 196608
  u16* Qf     = (u16*)(ws + 786944);     // 3145728 (Q frag layout)
  u16* Kf     = (u16*)(ws + 3932672);    // 3145728 (K frag layout)
  u16* Vfr    = (u16*)(ws + 7078400);    // 3145728 (V frag layout)
  u16* Vb     = (u16*)(ws + 10224128);   // 3145728 (V row-major bf16)
  float* out  = (float*)d_out;

  prep_kernel<<<1537, 256, 0, stream>>>(q_w, k_w, k_b, v_w, cn3_w, cn3_b,
                                        cn5_w, cn5_b, wefff, beff, qwf, vwf);
  dim3 g(128, 8);
  proj_split<4, 128, QIN, 0, 4><<<g, 256, 0, stream>>>(
      evo, qwf, q_b, Qf, nullptr);
  proj_split<4, 256, VIN, 2, 4><<<g, 256, 0, stream>>>(
      plm, vwf, v_b, Vfr, Vb);
  proj_split<5, 512, QIN, 1, 4><<<g, 320, 0, stream>>>(
      evo, wefff, beff, Kf, nullptr);
  attn_kernel<<<1024, 256, 0, stream>>>(Qf, Kf, Vfr, Vb, seqlen, out);
}

// Round 5
// 125.595 us; speedup vs baseline: 1.0160x; 1.0160x over previous
//
#include <hip/hip_runtime.h>

typedef unsigned short u16;
typedef unsigned int u32;
typedef float f32x4 __attribute__((ext_vector_type(4)));
typedef short s16x8 __attribute__((ext_vector_type(8)));

#define LSEQ 2048
#define QIN 512
#define VIN 1024
#define KCAT 704
#define KEFF 2560
#define NORMS 0.10206207261596575f  // 1/sqrt(96)

__device__ __forceinline__ u16 f2bf(float f) {
  u32 u = __float_as_uint(f);
  u = (u + 0x7fffu + ((u >> 16) & 1u)) >> 16;  // RNE
  return (u16)u;
}
__device__ __forceinline__ float bf2f(u16 v) {
  return __uint_as_float(((u32)v) << 16);
}

__device__ __forceinline__ s16x8 load8cvt(const float* __restrict__ p) {
  float4 a = *(const float4*)p;
  float4 b = *(const float4*)(p + 4);
  s16x8 r;
  r[0] = (short)f2bf(a.x); r[1] = (short)f2bf(a.y);
  r[2] = (short)f2bf(a.z); r[3] = (short)f2bf(a.w);
  r[4] = (short)f2bf(b.x); r[5] = (short)f2bf(b.y);
  r[6] = (short)f2bf(b.z); r[7] = (short)f2bf(b.w);
  return r;
}

// Fragment-linear index for a weight matrix W[N=96][K]:
// element W[o][k] -> ((kc*6 + nt)*64 + kg*16 + ln)*8 + j
__device__ __forceinline__ size_t wfrag_idx(int o, int k) {
  int kc = k >> 5, kg = (k >> 3) & 3, j = k & 7;
  int nt = o >> 4, ln = o & 15;
  return ((size_t)(kc * 6 + nt) * 64 + kg * 16 + ln) * 8 + j;
}

// ---------------------------------------------------------------------------
// Kernel 0: transpose conv weights to j-contiguous: c3t[t][c][j], c5t[t][c][j]
// ---------------------------------------------------------------------------
__global__ __launch_bounds__(256) void prep_transpose(
    const float* __restrict__ cn3_w, const float* __restrict__ cn5_w,
    float* __restrict__ c3t, float* __restrict__ c5t) {
  int idx = blockIdx.x * 256 + threadIdx.x;
  if (idx < 3 * 512 * 96) {
    int t = idx / (512 * 96);
    int rem = idx - t * 512 * 96;
    int c = rem / 96, j = rem - c * 96;
    c3t[idx] = cn3_w[(j * 512 + c) * 3 + t];
  } else {
    int i2 = idx - 3 * 512 * 96;   // < 5*512*96
    int t = i2 / (512 * 96);
    int rem = i2 - t * 512 * 96;
    int c = rem / 96, j = rem - c * 96;
    c5t[i2] = cn5_w[(j * 512 + c) * 5 + t];
  }
}

// ---------------------------------------------------------------------------
// Kernel 1: fold conv3/conv5 + k_w into W_eff (frag layout) + b_eff;
// convert q_w / v_w to frag-bf16.
// blocks: [0,960) W_eff (one o per 10 blocks), 960 b_eff,
//         [961,1153) q_w, [1153,1537) v_w.
// ---------------------------------------------------------------------------
__global__ __launch_bounds__(256) void prep_fold(
    const float* __restrict__ q_w, const float* __restrict__ k_w,
    const float* __restrict__ k_b, const float* __restrict__ v_w,
    const float* __restrict__ c3t, const float* __restrict__ cn3_b,
    const float* __restrict__ c5t, const float* __restrict__ cn5_b,
    u16* __restrict__ wefff, float* __restrict__ beff,
    u16* __restrict__ qwf, u16* __restrict__ vwf) {
  int blk = blockIdx.x, tid = threadIdx.x;
  if (blk < 960) {
    int o = blk / 10;
    int k = (blk - o * 10) * 256 + tid;
    int t = k >> 9, c = k & 511;
    const float* kwo = k_w + o * KCAT;
    float acc = (t == 2) ? kwo[c] : 0.f;
    if (t >= 1 && t <= 3) {
      const float* a = kwo + 512;
      const float* b = c3t + (size_t)((t - 1) * 512 + c) * 96;
      #pragma unroll
      for (int j = 0; j < 96; j += 4) {
        float4 bv = *(const float4*)(b + j);
        acc += a[j] * bv.x + a[j + 1] * bv.y + a[j + 2] * bv.z + a[j + 3] * bv.w;
      }
    }
    {
      const float* a = kwo + 608;
      const float* b = c5t + (size_t)(t * 512 + c) * 96;
      #pragma unroll
      for (int j = 0; j < 96; j += 4) {
        float4 bv = *(const float4*)(b + j);
        acc += a[j] * bv.x + a[j + 1] * bv.y + a[j + 2] * bv.z + a[j + 3] * bv.w;
      }
    }
    wefff[wfrag_idx(o, k)] = f2bf(acc);
  } else if (blk == 960) {
    if (tid < 96) {
      const float* kwo = k_w + tid * KCAT;
      float b = k_b[tid];
      for (int j = 0; j < 96; ++j)
        b += kwo[512 + j] * cn3_b[j] + kwo[608 + j] * cn5_b[j];
      beff[tid] = b;
    }
  } else if (blk < 1153) {              // q_w -> frag bf16 (96*512)
    int e = (blk - 961) * 256 + tid;
    int o = e >> 9, k = e & 511;
    qwf[wfrag_idx(o, k)] = f2bf(q_w[e]);
  } else {                              // v_w -> frag bf16 (96*1024)
    int e = (blk - 1153) * 256 + tid;
    int o = e >> 10, k = e & 1023;
    vwf[wfrag_idx(o, k)] = f2bf(v_w[e]);
  }
}

// ---------------------------------------------------------------------------
// Kernel 2: K-split projection GEMM, 32 rows/block (2 row-groups share each
// B-fragment), NW waves each own a K-slice (MODE 1: one conv tap, rows
// shifted by wid-2).  f32 A converted inline.  Epilogue reduces the NW
// partials via LDS in two 16-row passes.
// MODE 0: Q;  MODE 1: K-conv;  MODE 2: V (writes Vfrag + Vb row-major).
// ---------------------------------------------------------------------------
template <int NW, int KPW, int AKD, int MODE, int UNR>
__global__ __launch_bounds__(NW * 64, 2) void proj_split(
    const float* __restrict__ Xf, const u16* __restrict__ Wf,
    const float* __restrict__ bias, u16* __restrict__ OutFrag,
    u16* __restrict__ Vb) {
  __shared__ float Ls[NW][16][97];
  int bx = blockIdx.x, bb = blockIdx.y;
  int tid = threadIdx.x;
  int wid = tid >> 6, lane = tid & 63, ln = lane & 15, kg = lane >> 4;

  int r0 = bx * 32 + ln + (MODE == 1 ? wid - 2 : 0);
  int r1 = r0 + 16;
  bool ok0 = (MODE != 1) || (r0 >= 0 && r0 < LSEQ);
  bool ok1 = (MODE != 1) || (r1 < LSEQ);
  const float* x0 = Xf + ((size_t)bb * LSEQ + (ok0 ? r0 : 0)) * AKD +
                    (MODE == 1 ? 0 : wid * KPW);
  const float* x1 = Xf + ((size_t)bb * LSEQ + (ok1 ? r1 : 0)) * AKD +
                    (MODE == 1 ? 0 : wid * KPW);

  f32x4 acc0[6], acc1[6];
  #pragma unroll
  for (int nt = 0; nt < 6; ++nt) {
    acc0[nt] = (f32x4){0.f, 0.f, 0.f, 0.f};
    acc1[nt] = (f32x4){0.f, 0.f, 0.f, 0.f};
  }

  #pragma unroll UNR
  for (int kc = 0; kc < KPW / 32; ++kc) {
    int off = kc * 32 + kg * 8;
    s16x8 a0 = (s16x8){0, 0, 0, 0, 0, 0, 0, 0};
    s16x8 a1 = (s16x8){0, 0, 0, 0, 0, 0, 0, 0};
    if (ok0) a0 = load8cvt(x0 + off);
    if (ok1) a1 = load8cvt(x1 + off);
    const u16* wp = Wf + (size_t)(wid * (KPW / 32) + kc) * 3072 + lane * 8;
    #pragma unroll
    for (int nt = 0; nt < 6; ++nt) {
      s16x8 bf = *(const s16x8*)&wp[(size_t)nt * 512];
      acc0[nt] = __builtin_amdgcn_mfma_f32_16x16x32_bf16(a0, bf, acc0[nt], 0, 0, 0);
      acc1[nt] = __builtin_amdgcn_mfma_f32_16x16x32_bf16(a1, bf, acc1[nt], 0, 0, 0);
    }
  }

  #pragma unroll
  for (int half = 0; half < 2; ++half) {
    if (half) __syncthreads();
    #pragma unroll
    for (int nt = 0; nt < 6; ++nt)
      #pragma unroll
      for (int r = 0; r < 4; ++r)
        Ls[wid][kg * 4 + r][nt * 16 + ln] = half ? acc1[nt][r] : acc0[nt][r];
    __syncthreads();
    if (tid < 192) {
      int r = tid / 12, cg = tid % 12;
      s16x8 ov;
      #pragma unroll
      for (int e = 0; e < 8; ++e) {
        int c = cg * 8 + e;
        float s = bias[c];
        #pragma unroll
        for (int w = 0; w < NW; ++w) s += Ls[w][r][c];
        ov[e] = (short)f2bf(s);
      }
      if constexpr (MODE == 0 || MODE == 1) {
        size_t qt = (size_t)bb * 128 + bx * 2 + half;
        *(s16x8*)&OutFrag[((qt * 3 + (cg >> 2)) * 64 + (cg & 3) * 16 + r) * 8] = ov;
      } else {
        *(s16x8*)&Vb[((size_t)bb * LSEQ + bx * 32 + half * 16 + r) * 96 + cg * 8] = ov;
        // Vfrag: thread owns feature c, 8 consecutive keys
        int c = tid >> 1, kb = (tid & 1) + half * 2;
        s16x8 fv;
        #pragma unroll
        for (int e = 0; e < 8; ++e) {
          int lr = (tid & 1) * 8 + e;
          float s = bias[c];
          #pragma unroll
          for (int w = 0; w < NW; ++w) s += Ls[w][lr][c];
          fv[e] = (short)f2bf(s);
        }
        *(s16x8*)&OutFrag[((((size_t)bb * 64 + bx) * 6 + (c >> 4)) * 64 +
                           kb * 16 + (c & 15)) * 8] = fv;
      }
    }
  }
}

// ---------------------------------------------------------------------------
// Kernel 3: flash attention + "+V", key-split across 4 waves, all operands in
// fragment layout -> every global load is a coalesced 1KB wave load.
// 1D grid 1024, XCD-swizzled so each batch lives on one XCD's L2.
// ---------------------------------------------------------------------------
__global__ __launch_bounds__(256) void attn_kernel(
    const u16* __restrict__ Qf, const u16* __restrict__ Kf,
    const u16* __restrict__ Vfr, const u16* __restrict__ Vb,
    const int* __restrict__ seqlen, float* __restrict__ out) {
  __shared__ u16 Ps[4][16][40];       // per-wave P scratch
  __shared__ float Cacc[4][16][97];   // partial O
  __shared__ float Cml[4][16][2];     // partial m, l

  int bid = blockIdx.x;
  int swz = (bid & 7) * 128 + (bid >> 3);   // XCD x -> batch x
  int bb = swz >> 7, bx = swz & 127;
  int tid = threadIdx.x;
  int wid = tid >> 6, lane = tid & 63, ln = lane & 15, kg = lane >> 4;
  int n = seqlen[bb];
  int nkc = (n + 31) >> 5;

  size_t qt = (size_t)bb * 128 + bx;
  s16x8 aQ[3];
  #pragma unroll
  for (int kk = 0; kk < 3; ++kk)
    aQ[kk] = *(const s16x8*)&Qf[((qt * 3 + kk) * 64 + lane) * 8];

  float m[4], lsum[4];
  f32x4 acc[6];
  #pragma unroll
  for (int r = 0; r < 4; ++r) { m[r] = -1e30f; lsum[r] = 0.f; }
  #pragma unroll
  for (int nt = 0; nt < 6; ++nt) acc[nt] = (f32x4){0.f, 0.f, 0.f, 0.f};

  for (int kc = wid; kc < nkc; kc += 4) {
    int key0 = kc * 32;
    // ---- S = Q K^T; K-frags: two 16-key tiles, 3KB contiguous each ----
    const u16* kf0 = Kf + (((size_t)bb * 128 + kc * 2) * 3 * 64) * 8 + lane * 8;
    f32x4 s0 = (f32x4){0.f, 0.f, 0.f, 0.f};
    f32x4 s1 = (f32x4){0.f, 0.f, 0.f, 0.f};
    #pragma unroll
    for (int kk = 0; kk < 3; ++kk) {
      s16x8 b0 = *(const s16x8*)&kf0[(size_t)kk * 512];
      s0 = __builtin_amdgcn_mfma_f32_16x16x32_bf16(aQ[kk], b0, s0, 0, 0, 0);
      s16x8 b1 = *(const s16x8*)&kf0[(size_t)(3 + kk) * 512];
      s1 = __builtin_amdgcn_mfma_f32_16x16x32_bf16(aQ[kk], b1, s1, 0, 0, 0);
    }

    // ---- mask + scale, online softmax ----
    bool v0 = (key0 + ln) < n;
    bool v1 = (key0 + 16 + ln) < n;
    float sv0[4], sv1[4], mx[4];
    #pragma unroll
    for (int r = 0; r < 4; ++r) {
      sv0[r] = v0 ? s0[r] * NORMS : -1e30f;
      sv1[r] = v1 ? s1[r] * NORMS : -1e30f;
      mx[r] = fmaxf(sv0[r], sv1[r]);
    }
    #pragma unroll
    for (int r = 0; r < 4; ++r) {
      mx[r] = fmaxf(mx[r], __shfl_xor(mx[r], 1, 16));
      mx[r] = fmaxf(mx[r], __shfl_xor(mx[r], 2, 16));
      mx[r] = fmaxf(mx[r], __shfl_xor(mx[r], 4, 16));
      mx[r] = fmaxf(mx[r], __shfl_xor(mx[r], 8, 16));
    }
    float fac[4], p0[4], p1[4], rs[4];
    #pragma unroll
    for (int r = 0; r < 4; ++r) {
      float mn = fmaxf(m[r], mx[r]);
      fac[r] = __expf(m[r] - mn);
      p0[r] = __expf(sv0[r] - mn);
      p1[r] = __expf(sv1[r] - mn);
      rs[r] = p0[r] + p1[r];
      m[r] = mn;
    }
    #pragma unroll
    for (int r = 0; r < 4; ++r) {
      rs[r] += __shfl_xor(rs[r], 1, 16);
      rs[r] += __shfl_xor(rs[r], 2, 16);
      rs[r] += __shfl_xor(rs[r], 4, 16);
      rs[r] += __shfl_xor(rs[r], 8, 16);
      lsum[r] = lsum[r] * fac[r] + rs[r];
    }
    #pragma unroll
    for (int nt = 0; nt < 6; ++nt)
      #pragma unroll
      for (int r = 0; r < 4; ++r) acc[nt][r] *= fac[r];

    // ---- P (D-layout) -> per-wave LDS -> A-frag (bf16) ----
    u16* Pw = &Ps[wid][0][0];
    #pragma unroll
    for (int r = 0; r < 4; ++r) {
      Pw[(kg * 4 + r) * 40 + ln] = f2bf(p0[r]);
      Pw[(kg * 4 + r) * 40 + 16 + ln] = f2bf(p1[r]);
    }
    s16x8 pa = *(const s16x8*)&Pw[ln * 40 + kg * 8];

    // ---- acc += P @ V; V-frags 6KB contiguous ----
    const u16* vf = Vfr + (((size_t)bb * 64 + kc) * 6 * 64) * 8 + lane * 8;
    #pragma unroll
    for (int nt = 0; nt < 6; ++nt) {
      s16x8 bv = *(const s16x8*)&vf[(size_t)nt * 512];
      acc[nt] = __builtin_amdgcn_mfma_f32_16x16x32_bf16(pa, bv, acc[nt], 0, 0, 0);
    }
  }

  // ---- write partials ----
  #pragma unroll
  for (int nt = 0; nt < 6; ++nt)
    #pragma unroll
    for (int r = 0; r < 4; ++r)
      Cacc[wid][kg * 4 + r][nt * 16 + ln] = acc[nt][r];
  if (ln == 0) {
    #pragma unroll
    for (int r = 0; r < 4; ++r) {
      Cml[wid][kg * 4 + r][0] = m[r];
      Cml[wid][kg * 4 + r][1] = lsum[r];
    }
  }
  __syncthreads();

  // ---- combine 4 key-split partials + "+V" ----
  size_t obase = ((size_t)bb * LSEQ + bx * 16) * 96;
  for (int i = tid; i < 1536; i += 256) {
    int row = i / 96;
    float mg = -1e30f;
    #pragma unroll
    for (int w = 0; w < 4; ++w) mg = fmaxf(mg, Cml[w][row][0]);
    float lg = 0.f, av = 0.f;
    #pragma unroll
    for (int w = 0; w < 4; ++w) {
      float e = __expf(Cml[w][row][0] - mg);
      lg += Cml[w][row][1] * e;
      av += Cacc[w][row][i - row * 96] * e;
    }
    out[obase + i] = av / lg + bf2f(Vb[obase + i]);
  }
}

// ---------------------------------------------------------------------------
extern "C" void kernel_launch(void* const* d_in, const int* in_sizes, int n_in,
                              void* d_out, int out_size, void* d_ws,
                              size_t ws_size, hipStream_t stream) {
  const float* plm   = (const float*)d_in[0];
  const float* evo   = (const float*)d_in[1];
  const int* seqlen  = (const int*)d_in[2];
  const float* q_w   = (const float*)d_in[3];
  const float* q_b   = (const float*)d_in[4];
  const float* k_w   = (const float*)d_in[5];
  const float* k_b   = (const float*)d_in[6];
  const float* v_w   = (const float*)d_in[7];
  const float* v_b   = (const float*)d_in[8];
  const float* cn3_w = (const float*)d_in[9];
  const float* cn3_b = (const float*)d_in[10];
  const float* cn5_w = (const float*)d_in[11];
  const float* cn5_b = (const float*)d_in[12];

  char* ws = (char*)d_ws;
  u16* wefff  = (u16*)(ws + 0);           // 491520
  float* beff = (float*)(ws + 491520);    // 512
  u16* qwf    = (u16*)(ws + 492032);      // 98304
  u16* vwf    = (u16*)(ws + 590336);      // 196608
  float* c3t  = (float*)(ws + 786944);    // 589824
  float* c5t  = (float*)(ws + 1376768);   // 983040
  u16* Qf     = (u16*)(ws + 2359808);     // 3145728 (Q frag layout)
  u16* Kf     = (u16*)(ws + 5505536);     // 3145728 (K frag layout)
  u16* Vfr    = (u16*)(ws + 8651264);     // 3145728 (V frag layout)
  u16* Vb     = (u16*)(ws + 11796992);    // 3145728 (V row-major bf16)
  float* out  = (float*)d_out;

  prep_transpose<<<1536, 256, 0, stream>>>(cn3_w, cn5_w, c3t, c5t);
  prep_fold<<<1537, 256, 0, stream>>>(q_w, k_w, k_b, v_w, c3t, cn3_b,
                                      c5t, cn5_b, wefff, beff, qwf, vwf);
  dim3 g(64, 8);
  proj_split<4, 128, QIN, 0, 4><<<g, 256, 0, stream>>>(
      evo, qwf, q_b, Qf, nullptr);
  proj_split<4, 256, VIN, 2, 4><<<g, 256, 0, stream>>>(
      plm, vwf, v_b, Vfr, Vb);
  proj_split<5, 512, QIN, 1, 4><<<g, 320, 0, stream>>>(
      evo, wefff, beff, Kf, nullptr);
  attn_kernel<<<1024, 256, 0, stream>>>(Qf, Kf, Vfr, Vb, seqlen, out);
}